// Round 3
// baseline (957.904 us; speedup 1.0000x reference)
//
#include <hip/hip_runtime.h>

// VGAE on MI355X — round 5: dispatch-count collapse (10 -> 2).
// Theory: per-kernel arithmetic sums to ~200 us but measured 575; no single
// kernel exceeds ~250 us (top-5 = harness fills) => the missing ~350 us is
// spread across 10 launch boundaries. Fix: one persistent mega-kernel
// (448 blocks x 256 thr, 64 KB LDS, 2 blocks/CU guaranteed co-resident)
// with agent-scope device barriers between phases. Phase math identical to
// round 4. k_barzero resets barrier slots each iteration (ws is re-poisoned).
// Barrier is deadlock-free by construction: every block increments every
// slot, target = NBLK, unsigned compare (stale/poison values >= NBLK fall
// through; rocprof replay without barzero cannot hang).
//
// Pipeline (phases inside k_mega):
//   S0 init deg/cnt + zero z pad rows
//   S1 edge atomics (deg, cnt)
//   S2 dis=rsqrt (blocks 1..) || CSR scan (block 0)
//   S3 CSR fill (norm inline)
//   S4 hw1 = x@W1            (f32 LDS GEMM, grid-stride tiles)
//   S5 h    = relu(d^2*hw1 + b1 + gather)
//   S6 hagg = d^2*h + gather
//   S7 zh,zl = bf16-split(hagg@[W2|W3] + b + noise*exp(.))
//   S8 out = sigmoid(z@z^T)  (3-term bf16 MFMA, LDS-staged, grid-stride)

#define Nn 10000
#define Np 10112            // 79*128, padded rows for decode
#define NpK (Np * 64)
#define NBLK 448            // capacity at 64KB LDS is 512 (2/CU); 448 = margin
#define NTHR (NBLK * 256)
#define NTILE (79 * 79)

typedef short short8 __attribute__((ext_vector_type(8)));
typedef float f32x4 __attribute__((ext_vector_type(4)));
typedef unsigned short ushort4e __attribute__((ext_vector_type(4)));

union SmemT {
  struct { short zhr[128][64]; short zlr[128][64]; short zhc[128][64]; short zlc[128][64]; } d;  // 64 KB
  struct { float xs[16][68]; float ws[64][128]; float zs[16][128]; } g;                          // 45 KB
  int partial[256];
};

static __device__ __forceinline__ float sigmoidf(float v) {
  return __builtin_amdgcn_rcpf(1.0f + __expf(-v));
}
static __device__ __forceinline__ unsigned short f32_to_bf16(float f) {
  unsigned int u = __float_as_uint(f);
  unsigned int r = (u + 0x7FFF + ((u >> 16) & 1)) >> 16;  // RNE
  return (unsigned short)r;
}
static __device__ __forceinline__ float bf16_to_f32(unsigned short s) {
  return __uint_as_float(((unsigned int)s) << 16);
}

// device-wide barrier: release add, relaxed agent polls (no L2-inv storm),
// one agent fence on exit. Always terminates: all NBLK blocks add 1.
static __device__ __forceinline__ void gsync(unsigned* bar, int slot) {
  __syncthreads();
  if (threadIdx.x == 0) {
    __hip_atomic_fetch_add(&bar[slot], 1u, __ATOMIC_RELEASE, __HIP_MEMORY_SCOPE_AGENT);
    while (__hip_atomic_load(&bar[slot], __ATOMIC_RELAXED, __HIP_MEMORY_SCOPE_AGENT) < (unsigned)NBLK)
      __builtin_amdgcn_s_sleep(2);
    __threadfence();  // acquire: see all phase writes published before arrivals
  }
  __syncthreads();
}

__global__ void k_barzero(unsigned* __restrict__ bar) {
  if (threadIdx.x < 16) bar[threadIdx.x] = 0;
}

__global__ __launch_bounds__(256, 2) void k_mega(
    const float* __restrict__ x, const int* __restrict__ erow, const int* __restrict__ ecol,
    const float* __restrict__ ew, const float* __restrict__ noise,
    const float* __restrict__ W1, const float* __restrict__ b1,
    const float* __restrict__ W2, const float* __restrict__ b2,
    const float* __restrict__ W3, const float* __restrict__ b3,
    float* __restrict__ out, float* __restrict__ dis,
    unsigned short* __restrict__ zh, unsigned short* __restrict__ zl,
    unsigned* __restrict__ bar, int E) {
  __shared__ SmemT sm;
  const int tid = threadIdx.x;
  const int bid = blockIdx.x;
  const int gid = bid * 256 + tid;

  // scratch in out (all dead before decode overwrites out)
  float* S = out;
  float* hw1  = S;                       // n*128
  float* h    = S + 1310720;             // n*128
  float* hagg = S + 2621440;             // n*128
  float* csr_w = S + 5242880;            // E
  int* csr_src = (int*)(S + 5402880);    // E
  int* ofs     = (int*)(S + 5562880);    // n+1
  int* ofs2    = (int*)(S + 5572896);    // n+1
  int* cnt     = (int*)(S + 5582912);    // n

  // ---- S0: init deg(=dis array)=1, cnt=0; zero z pad rows ----
  if (gid < Nn) { dis[gid] = 1.0f; cnt[gid] = 0; }
  if (gid < (Np - Nn) * 64) { zh[Nn * 64 + gid] = 0; zl[Nn * 64 + gid] = 0; }
  gsync(bar, 0);

  // ---- S1: edge atomics ----
  for (int e = gid; e < E; e += NTHR) {
    int c = ecol[e];
    atomicAdd(&dis[c], ew[e]);
    atomicAdd(&cnt[c], 1);
  }
  gsync(bar, 1);

  // ---- S2: block 0 does CSR scan; blocks 1.. compute dis=rsqrt ----
  if (bid == 0) {
    const int CH = (Nn + 255) / 256;
    const int start = tid * CH;
    int local = 0;
    for (int j = 0; j < CH; ++j) {
      int idx = start + j;
      if (idx < Nn) local += cnt[idx];
    }
    sm.partial[tid] = local;
    __syncthreads();
    for (int off = 1; off < 256; off <<= 1) {
      int v = (tid >= off) ? sm.partial[tid - off] : 0;
      __syncthreads();
      sm.partial[tid] += v;
      __syncthreads();
    }
    int run = sm.partial[tid] - local;  // exclusive prefix
    for (int j = 0; j < CH; ++j) {
      int idx = start + j;
      if (idx < Nn) { ofs[idx] = run; ofs2[idx] = run; run += cnt[idx]; }
    }
    if (tid == 255) { ofs[Nn] = run; ofs2[Nn] = run; }
  } else {
    int i = (bid - 1) * 256 + tid;
    if (i < Nn) { float dv = dis[i]; dis[i] = (dv > 0.0f) ? rsqrtf(dv) : 0.0f; }
  }
  gsync(bar, 2);

  // ---- S3: CSR fill (norm inline) ----
  for (int e = gid; e < E; e += NTHR) {
    int r = erow[e], c = ecol[e];
    int p = atomicAdd(&ofs2[c], 1);
    csr_src[p] = r;
    csr_w[p] = dis[r] * ew[e] * dis[c];
  }
  gsync(bar, 3);

  // ---- S4: hw1 = x @ W1, grid-stride over 625 row-tiles ----
  for (int rb = bid; rb < 625; rb += NBLK) {
    const int row0 = rb * 16;
    const int j0 = (tid & 31) * 4;
    const int r0 = (tid >> 5) * 2;
    const int lr = tid >> 4, lk = tid & 15;
    float acc0[4] = {0, 0, 0, 0}, acc1[4] = {0, 0, 0, 0};
    for (int k0 = 0; k0 < 256; k0 += 64) {
      *(float4*)&sm.g.xs[lr][lk * 4] = *(const float4*)&x[(row0 + lr) * 256 + k0 + lk * 4];
#pragma unroll
      for (int it = 0; it < 8; ++it) {
        int idx4 = tid + it * 256;
        int kk = idx4 >> 5, jq = idx4 & 31;
        *(float4*)&sm.g.ws[kk][jq * 4] = *(const float4*)&W1[(k0 + kk) * 128 + jq * 4];
      }
      __syncthreads();
#pragma unroll 8
      for (int kk = 0; kk < 64; ++kk) {
        float a0 = sm.g.xs[r0][kk], a1 = sm.g.xs[r0 + 1][kk];
        float4 w = *(const float4*)&sm.g.ws[kk][j0];
        acc0[0] += a0 * w.x; acc0[1] += a0 * w.y; acc0[2] += a0 * w.z; acc0[3] += a0 * w.w;
        acc1[0] += a1 * w.x; acc1[1] += a1 * w.y; acc1[2] += a1 * w.z; acc1[3] += a1 * w.w;
      }
      __syncthreads();
    }
    *(float4*)&hw1[(row0 + r0) * 128 + j0] = make_float4(acc0[0], acc0[1], acc0[2], acc0[3]);
    *(float4*)&hw1[(row0 + r0 + 1) * 128 + j0] = make_float4(acc1[0], acc1[1], acc1[2], acc1[3]);
  }
  gsync(bar, 4);

  // ---- S5/S6: CSR aggregation (wave per node, grid-stride) ----
  // mode 0: h = relu(d^2*hw1 + b1 + gather(norm*hw1))
  {
    const int f2 = tid & 63;
    const float2* featv = (const float2*)hw1;
    for (int node = bid * 4 + (tid >> 6); node < Nn; node += NBLK * 4) {
      int s = ofs[node], e = ofs[node + 1];
      float d = dis[node];
      float2 self = featv[node * 64 + f2];
      float accx = d * d * self.x, accy = d * d * self.y;
      int j = s;
      for (; j + 2 <= e; j += 2) {
        int r0 = csr_src[j], r1 = csr_src[j + 1];
        float w0 = csr_w[j], w1 = csr_w[j + 1];
        float2 v0 = featv[r0 * 64 + f2];
        float2 v1 = featv[r1 * 64 + f2];
        accx += w0 * v0.x + w1 * v1.x;
        accy += w0 * v0.y + w1 * v1.y;
      }
      if (j < e) {
        int r0 = csr_src[j];
        float w0 = csr_w[j];
        float2 v0 = featv[r0 * 64 + f2];
        accx += w0 * v0.x;
        accy += w0 * v0.y;
      }
      float2 bb = ((const float2*)b1)[f2];
      float2 o;
      o.x = fmaxf(accx + bb.x, 0.0f);
      o.y = fmaxf(accy + bb.y, 0.0f);
      ((float2*)h)[node * 64 + f2] = o;
    }
  }
  gsync(bar, 5);
  // mode 1: hagg = d^2*h + gather(norm*h)
  {
    const int f2 = tid & 63;
    const float2* featv = (const float2*)h;
    for (int node = bid * 4 + (tid >> 6); node < Nn; node += NBLK * 4) {
      int s = ofs[node], e = ofs[node + 1];
      float d = dis[node];
      float2 self = featv[node * 64 + f2];
      float accx = d * d * self.x, accy = d * d * self.y;
      int j = s;
      for (; j + 2 <= e; j += 2) {
        int r0 = csr_src[j], r1 = csr_src[j + 1];
        float w0 = csr_w[j], w1 = csr_w[j + 1];
        float2 v0 = featv[r0 * 64 + f2];
        float2 v1 = featv[r1 * 64 + f2];
        accx += w0 * v0.x + w1 * v1.x;
        accy += w0 * v0.y + w1 * v1.y;
      }
      if (j < e) {
        int r0 = csr_src[j];
        float w0 = csr_w[j];
        float2 v0 = featv[r0 * 64 + f2];
        accx += w0 * v0.x;
        accy += w0 * v0.y;
      }
      float2 o; o.x = accx; o.y = accy;
      ((float2*)hagg)[node * 64 + f2] = o;
    }
  }
  gsync(bar, 6);

  // ---- S7: [mean|lstd] GEMM + reparam + bf16 split -> zh, zl ----
  for (int rb = bid; rb < 625; rb += NBLK) {
    const int row0 = rb * 16;
    const int j0 = (tid & 31) * 4;
    const int r0 = (tid >> 5) * 2;
    const int lr = tid >> 4, lk = tid & 15;
    float acc0[4] = {0, 0, 0, 0}, acc1[4] = {0, 0, 0, 0};
    for (int k0 = 0; k0 < 128; k0 += 64) {
      *(float4*)&sm.g.xs[lr][lk * 4] = *(const float4*)&hagg[(row0 + lr) * 128 + k0 + lk * 4];
#pragma unroll
      for (int it = 0; it < 8; ++it) {
        int idx4 = tid + it * 256;
        int kk = idx4 >> 5, jq = idx4 & 31;
        int j = jq * 4;
        float4 wv;
        if (j < 64) wv = *(const float4*)&W2[(k0 + kk) * 64 + j];
        else        wv = *(const float4*)&W3[(k0 + kk) * 64 + (j - 64)];
        *(float4*)&sm.g.ws[kk][j] = wv;
      }
      __syncthreads();
#pragma unroll 8
      for (int kk = 0; kk < 64; ++kk) {
        float a0 = sm.g.xs[r0][kk], a1 = sm.g.xs[r0 + 1][kk];
        float4 w = *(const float4*)&sm.g.ws[kk][j0];
        acc0[0] += a0 * w.x; acc0[1] += a0 * w.y; acc0[2] += a0 * w.z; acc0[3] += a0 * w.w;
        acc1[0] += a1 * w.x; acc1[1] += a1 * w.y; acc1[2] += a1 * w.z; acc1[3] += a1 * w.w;
      }
      __syncthreads();
    }
    {
      float4 bb = (j0 < 64) ? *(const float4*)&b2[j0] : *(const float4*)&b3[j0 - 64];
      sm.g.zs[r0][j0 + 0] = acc0[0] + bb.x; sm.g.zs[r0][j0 + 1] = acc0[1] + bb.y;
      sm.g.zs[r0][j0 + 2] = acc0[2] + bb.z; sm.g.zs[r0][j0 + 3] = acc0[3] + bb.w;
      sm.g.zs[r0 + 1][j0 + 0] = acc1[0] + bb.x; sm.g.zs[r0 + 1][j0 + 1] = acc1[1] + bb.y;
      sm.g.zs[r0 + 1][j0 + 2] = acc1[2] + bb.z; sm.g.zs[r0 + 1][j0 + 3] = acc1[3] + bb.w;
    }
    __syncthreads();
    {
      const int r = tid >> 4;
      const int jj = (tid & 15) * 4;
      float4 mn = *(const float4*)&sm.g.zs[r][jj];
      float4 ls = *(const float4*)&sm.g.zs[r][64 + jj];
      float4 nz = *(const float4*)&noise[(row0 + r) * 64 + jj];
      float z0 = mn.x + nz.x * __expf(ls.x);
      float z1 = mn.y + nz.y * __expf(ls.y);
      float z2 = mn.z + nz.z * __expf(ls.z);
      float z3 = mn.w + nz.w * __expf(ls.w);
      ushort4e hh, ll;
      hh[0] = f32_to_bf16(z0); ll[0] = f32_to_bf16(z0 - bf16_to_f32(hh[0]));
      hh[1] = f32_to_bf16(z1); ll[1] = f32_to_bf16(z1 - bf16_to_f32(hh[1]));
      hh[2] = f32_to_bf16(z2); ll[2] = f32_to_bf16(z2 - bf16_to_f32(hh[2]));
      hh[3] = f32_to_bf16(z3); ll[3] = f32_to_bf16(z3 - bf16_to_f32(hh[3]));
      *(ushort4e*)&zh[(row0 + r) * 64 + jj] = hh;
      *(ushort4e*)&zl[(row0 + r) * 64 + jj] = ll;
    }
    __syncthreads();  // zs reads done before next tile restages
  }
  gsync(bar, 7);

  // ---- S8: decode, grid-stride over 79x79 tiles ----
  const int wave = tid >> 6, lane = tid & 63;
  const int lr0 = (wave >> 1) * 64;
  const int lc0 = (wave & 1) * 64;
  const int lrow = lane & 15;
  const int quad = lane >> 4;
  for (int t = bid; t < NTILE; t += NBLK) {
    const int R0 = (t / 79) * 128;
    const int C0 = (t % 79) * 128;
    __syncthreads();  // previous tile's LDS reads complete
    {
      const int seg = tid & 7;
#pragma unroll
      for (int p = 0; p < 4; ++p) {
        const int rr = (p << 5) + (tid >> 3);
        const int sw = (seg ^ (rr & 7)) * 8;
        short8 vhr = *(const short8*)&zh[(size_t)(R0 + rr) * 64 + seg * 8];
        short8 vlr = *(const short8*)&zl[(size_t)(R0 + rr) * 64 + seg * 8];
        short8 vhc = *(const short8*)&zh[(size_t)(C0 + rr) * 64 + seg * 8];
        short8 vlc = *(const short8*)&zl[(size_t)(C0 + rr) * 64 + seg * 8];
        *(short8*)&sm.d.zhr[rr][sw] = vhr;
        *(short8*)&sm.d.zlr[rr][sw] = vlr;
        *(short8*)&sm.d.zhc[rr][sw] = vhc;
        *(short8*)&sm.d.zlc[rr][sw] = vlc;
      }
    }
    __syncthreads();

    f32x4 acc[4][4];
#pragma unroll
    for (int m = 0; m < 4; ++m)
#pragma unroll
      for (int nn = 0; nn < 4; ++nn) acc[m][nn] = (f32x4){0.0f, 0.0f, 0.0f, 0.0f};

#pragma unroll
    for (int kc = 0; kc < 64; kc += 32) {
      const int cb = (kc >> 3) + quad;
      short8 rh[4], rl[4], ch[4], cl[4];
#pragma unroll
      for (int m = 0; m < 4; ++m) {
        int row = lr0 + m * 16 + lrow;
        int sw = (cb ^ (row & 7)) * 8;
        rh[m] = *(const short8*)&sm.d.zhr[row][sw];
        rl[m] = *(const short8*)&sm.d.zlr[row][sw];
      }
#pragma unroll
      for (int nn = 0; nn < 4; ++nn) {
        int row = lc0 + nn * 16 + lrow;
        int sw = (cb ^ (row & 7)) * 8;
        ch[nn] = *(const short8*)&sm.d.zhc[row][sw];
        cl[nn] = *(const short8*)&sm.d.zlc[row][sw];
      }
#pragma unroll
      for (int m = 0; m < 4; ++m)
#pragma unroll
        for (int nn = 0; nn < 4; ++nn) {
          acc[m][nn] = __builtin_amdgcn_mfma_f32_16x16x32_bf16(ch[nn], rh[m], acc[m][nn], 0, 0, 0);
          acc[m][nn] = __builtin_amdgcn_mfma_f32_16x16x32_bf16(cl[nn], rh[m], acc[m][nn], 0, 0, 0);
          acc[m][nn] = __builtin_amdgcn_mfma_f32_16x16x32_bf16(ch[nn], rl[m], acc[m][nn], 0, 0, 0);
        }
    }

    // transposed C layout: lane holds row (R0+lr0+m*16+lrow), cols quad*4+r
#pragma unroll
    for (int m = 0; m < 4; ++m) {
      int gr = R0 + lr0 + m * 16 + lrow;
      if (gr >= Nn) continue;
#pragma unroll
      for (int nn = 0; nn < 4; ++nn) {
        int c0 = C0 + lc0 + nn * 16 + quad * 4;
        if (c0 >= Nn) continue;
        f32x4 v;
        v[0] = sigmoidf(acc[m][nn][0]);
        v[1] = sigmoidf(acc[m][nn][1]);
        v[2] = sigmoidf(acc[m][nn][2]);
        v[3] = sigmoidf(acc[m][nn][3]);
        *(f32x4*)&out[(size_t)gr * Nn + c0] = v;
      }
    }
  }
}

extern "C" void kernel_launch(void* const* d_in, const int* in_sizes, int n_in,
                              void* d_out, int out_size, void* d_ws, size_t ws_size,
                              hipStream_t stream) {
  const float* x     = (const float*)d_in[0];
  const int*   ei    = (const int*)d_in[1];
  const float* ew    = (const float*)d_in[2];
  const float* noise = (const float*)d_in[3];
  const float* W1    = (const float*)d_in[4];
  const float* b1    = (const float*)d_in[5];
  const float* W2    = (const float*)d_in[6];
  const float* b2    = (const float*)d_in[7];
  const float* W3    = (const float*)d_in[8];
  const float* b3    = (const float*)d_in[9];
  const int E = in_sizes[2];
  const int* row = ei;
  const int* col = ei + E;

  // d_ws: dis (40 KB) + zh + zl (~2.6 MB) + bar (64 B)
  float* dis = (float*)d_ws;
  unsigned short* zh = (unsigned short*)((char*)d_ws + 10240 * 4);
  unsigned short* zl = zh + NpK;
  unsigned* bar = (unsigned*)((char*)d_ws + 10240 * 4 + (size_t)2 * NpK * 2);

  k_barzero<<<1, 64, 0, stream>>>(bar);
  k_mega<<<NBLK, 256, 0, stream>>>(x, row, col, ew, noise, W1, b1, W2, b2, W3, b3,
                                   (float*)d_out, dis, zh, zl, bar, E);
}

// Round 4
// 559.364 us; speedup vs baseline: 1.7125x; 1.7125x over previous
//
#include <hip/hip_runtime.h>

// VGAE on MI355X — round 6: revert mega-kernel (it serialized latency-bound
// phases at 2 blocks/CU: 628 us vs ~245 us sum-of-parts). Round-5 taught us
// dur_us carries a ~330 us fixed harness term (1.6 GB poison fill), so the
// controllable budget is ~245 us. This round harvests concurrency + fusion:
//   - hipMemsetAsync zeroes deg+cnt (replaces k_init); dis = rsqrt(deg+1)
//   - k_front: gemm1 tiles (625 blocks) || edge atomics (157 blocks) -- the
//     two are independent; gemm1 hides under atomic latency
//   - k_mid: CSR scan (block 0) || dis=rsqrt (blocks 1-40) || z-pad zero
//     (blocks 41-47)
//   - k_aggemm: fused agg(mode1)+gemm2z: gather 16 hagg rows into LDS, then
//     [W2|W3] GEMM + reparam + bf16 split (kills hagg 5MB round-trip + launch)
//   - k_agg(mode0), k_fill, k_decode unchanged from round 4 (proven best)
// 7 dispatches total.

#define Nn 10000
#define Np 10112          // 79*128, padded rows for decode
#define NpK (Np * 64)

typedef short short8 __attribute__((ext_vector_type(8)));
typedef float f32x4 __attribute__((ext_vector_type(4)));
typedef unsigned short ushort4e __attribute__((ext_vector_type(4)));

static __device__ __forceinline__ float sigmoidf(float v) {
  return __builtin_amdgcn_rcpf(1.0f + __expf(-v));
}
static __device__ __forceinline__ unsigned short f32_to_bf16(float f) {
  unsigned int u = __float_as_uint(f);
  unsigned int r = (u + 0x7FFF + ((u >> 16) & 1)) >> 16;  // RNE
  return (unsigned short)r;
}
static __device__ __forceinline__ float bf16_to_f32(unsigned short s) {
  return __uint_as_float(((unsigned int)s) << 16);
}

// gemm1 tiles (blocks 0..624) || edge atomics (blocks 625..781).
// deg/cnt pre-zeroed by hipMemsetAsync; deg accumulates edge weights only.
__global__ __launch_bounds__(256) void k_front(const float* __restrict__ x,
                                               const float* __restrict__ W1,
                                               float* __restrict__ hw1,
                                               const int* __restrict__ ecol,
                                               const float* __restrict__ ew,
                                               float* __restrict__ deg,
                                               int* __restrict__ cnt, int E) {
  const int tid = threadIdx.x;
  const int bid = blockIdx.x;
  if (bid >= 625) {
    // edge atomics, grid-stride over E with 157*256 threads
    for (int e = (bid - 625) * 256 + tid; e < E; e += 157 * 256) {
      int c = ecol[e];
      atomicAdd(&deg[c], ew[e]);
      atomicAdd(&cnt[c], 1);
    }
    return;
  }
  __shared__ float xs[16][68];
  __shared__ float ws[64][128];
  const int row0 = bid * 16;
  const int j0 = (tid & 31) * 4;
  const int r0 = (tid >> 5) * 2;
  const int lr = tid >> 4, lk = tid & 15;
  float acc0[4] = {0, 0, 0, 0}, acc1[4] = {0, 0, 0, 0};
  for (int k0 = 0; k0 < 256; k0 += 64) {
    *(float4*)&xs[lr][lk * 4] = *(const float4*)&x[(row0 + lr) * 256 + k0 + lk * 4];
#pragma unroll
    for (int it = 0; it < 8; ++it) {
      int idx4 = tid + it * 256;
      int kk = idx4 >> 5, jq = idx4 & 31;
      *(float4*)&ws[kk][jq * 4] = *(const float4*)&W1[(k0 + kk) * 128 + jq * 4];
    }
    __syncthreads();
#pragma unroll 8
    for (int kk = 0; kk < 64; ++kk) {
      float a0 = xs[r0][kk], a1 = xs[r0 + 1][kk];
      float4 w = *(const float4*)&ws[kk][j0];
      acc0[0] += a0 * w.x; acc0[1] += a0 * w.y; acc0[2] += a0 * w.z; acc0[3] += a0 * w.w;
      acc1[0] += a1 * w.x; acc1[1] += a1 * w.y; acc1[2] += a1 * w.z; acc1[3] += a1 * w.w;
    }
    __syncthreads();
  }
  *(float4*)&hw1[(row0 + r0) * 128 + j0] = make_float4(acc0[0], acc0[1], acc0[2], acc0[3]);
  *(float4*)&hw1[(row0 + r0 + 1) * 128 + j0] = make_float4(acc1[0], acc1[1], acc1[2], acc1[3]);
}

// block 0: exclusive scan of cnt -> ofs, ofs2; blocks 1..40: dis=rsqrt(deg+1);
// blocks 41..47: zero zh/zl pad rows (Nn..Np).
__global__ __launch_bounds__(256) void k_mid(const int* __restrict__ cnt,
                                             int* __restrict__ ofs, int* __restrict__ ofs2,
                                             float* __restrict__ deg,
                                             unsigned short* __restrict__ zh,
                                             unsigned short* __restrict__ zl) {
  const int tid = threadIdx.x;
  const int bid = blockIdx.x;
  if (bid == 0) {
    __shared__ int partial[256];
    const int CH = (Nn + 255) / 256;
    const int start = tid * CH;
    int local = 0;
    for (int j = 0; j < CH; ++j) {
      int idx = start + j;
      if (idx < Nn) local += cnt[idx];
    }
    partial[tid] = local;
    __syncthreads();
    for (int off = 1; off < 256; off <<= 1) {
      int v = (tid >= off) ? partial[tid - off] : 0;
      __syncthreads();
      partial[tid] += v;
      __syncthreads();
    }
    int run = partial[tid] - local;  // exclusive prefix
    for (int j = 0; j < CH; ++j) {
      int idx = start + j;
      if (idx < Nn) { ofs[idx] = run; ofs2[idx] = run; run += cnt[idx]; }
    }
    if (tid == 255) { ofs[Nn] = run; ofs2[Nn] = run; }
  } else if (bid <= 40) {
    int i = (bid - 1) * 256 + tid;
    if (i < Nn) deg[i] = rsqrtf(deg[i] + 1.0f);  // deg >= 0, +1 self-loop
  } else {
    int local = (bid - 41) * 256 + tid;   // 7 blocks cover 1792 ushort4 chunks
    if (local < (Np - Nn) * 64 / 4) {
      ((ushort4e*)(zh + Nn * 64))[local] = (ushort4e){0, 0, 0, 0};
      ((ushort4e*)(zl + Nn * 64))[local] = (ushort4e){0, 0, 0, 0};
    }
  }
}

// place edges: csr_src[p]=row, csr_w[p]=dis[row]*ew*dis[col]
__global__ void k_fill(const int* __restrict__ row, const int* __restrict__ col,
                       const float* __restrict__ ew, const float* __restrict__ dis,
                       int* __restrict__ ofs2, int* __restrict__ csr_src,
                       float* __restrict__ csr_w, int E) {
  int e = blockIdx.x * 256 + threadIdx.x;
  if (e < E) {
    int r = row[e], c = col[e];
    int p = atomicAdd(&ofs2[c], 1);
    csr_src[p] = r;
    csr_w[p] = dis[r] * ew[e] * dis[c];
  }
}

// CSR aggregation mode0: h = relu(d^2*feat + b1 + gather(norm*feat)).
// 4 nodes/block (1 wave each), float2 per lane, 2-deep pipelined gather.
__global__ __launch_bounds__(256) void k_agg(const int* __restrict__ ofs,
                                             const int* __restrict__ csr_src,
                                             const float* __restrict__ csr_w,
                                             const float* __restrict__ feat,
                                             const float* __restrict__ dis,
                                             const float* __restrict__ b,
                                             float* __restrict__ out, int n) {
  int node = blockIdx.x * 4 + (threadIdx.x >> 6);
  if (node >= n) return;
  int f2 = threadIdx.x & 63;
  const float2* featv = (const float2*)feat;
  int s = ofs[node], e = ofs[node + 1];
  float d = dis[node];
  float2 self = featv[node * 64 + f2];
  float accx = d * d * self.x, accy = d * d * self.y;
  int j = s;
  for (; j + 2 <= e; j += 2) {
    int r0 = csr_src[j], r1 = csr_src[j + 1];
    float w0 = csr_w[j], w1 = csr_w[j + 1];
    float2 v0 = featv[r0 * 64 + f2];
    float2 v1 = featv[r1 * 64 + f2];
    accx += w0 * v0.x + w1 * v1.x;
    accy += w0 * v0.y + w1 * v1.y;
  }
  if (j < e) {
    int r0 = csr_src[j];
    float w0 = csr_w[j];
    float2 v0 = featv[r0 * 64 + f2];
    accx += w0 * v0.x;
    accy += w0 * v0.y;
  }
  float2 bb = ((const float2*)b)[f2];
  float2 o;
  o.x = fmaxf(accx + bb.x, 0.0f);
  o.y = fmaxf(accy + bb.y, 0.0f);
  ((float2*)out)[node * 64 + f2] = o;
}

// Fused agg(mode1) + gemm2 + reparam + bf16 split.
// Block = 16 nodes: phase A gathers hagg rows (wave per node, 4 nodes/wave
// sequential) into LDS; phase B: [mean|lstd] = xsf @ [W2|W3] + [b2|b3];
// phase C: z = mean + noise*exp(lstd) -> zh/zl.
__global__ __launch_bounds__(256) void k_aggemm(const int* __restrict__ ofs,
                                                const int* __restrict__ csr_src,
                                                const float* __restrict__ csr_w,
                                                const float* __restrict__ feat,  // h
                                                const float* __restrict__ dis,
                                                const float* __restrict__ W2, const float* __restrict__ W3,
                                                const float* __restrict__ b2, const float* __restrict__ b3,
                                                const float* __restrict__ noise,
                                                unsigned short* __restrict__ zh,
                                                unsigned short* __restrict__ zl) {
  __shared__ float xsf[16][130];   // gathered hagg rows (padded stride)
  __shared__ float ws[64][128];
  __shared__ float zs[16][128];
  const int tid = threadIdx.x;
  const int row0 = blockIdx.x * 16;
  const int w = tid >> 6, f2 = tid & 63;
  const float2* featv = (const float2*)feat;

  // phase A: gather aggregation for nodes row0 + w*4 + i
#pragma unroll
  for (int i = 0; i < 4; ++i) {
    const int nl = w * 4 + i;
    const int node = row0 + nl;
    int s = ofs[node], e = ofs[node + 1];
    float d = dis[node];
    float2 self = featv[node * 64 + f2];
    float accx = d * d * self.x, accy = d * d * self.y;
    int j = s;
    for (; j + 2 <= e; j += 2) {
      int r0 = csr_src[j], r1 = csr_src[j + 1];
      float w0 = csr_w[j], w1 = csr_w[j + 1];
      float2 v0 = featv[r0 * 64 + f2];
      float2 v1 = featv[r1 * 64 + f2];
      accx += w0 * v0.x + w1 * v1.x;
      accy += w0 * v0.y + w1 * v1.y;
    }
    if (j < e) {
      int r0 = csr_src[j];
      float w0 = csr_w[j];
      float2 v0 = featv[r0 * 64 + f2];
      accx += w0 * v0.x;
      accy += w0 * v0.y;
    }
    *(float2*)&xsf[nl][2 * f2] = make_float2(accx, accy);
  }
  __syncthreads();

  // phase B: GEMM 16x128 @ 128x[64|64]
  const int j0 = (tid & 31) * 4;
  const int r0 = (tid >> 5) * 2;
  float acc0[4] = {0, 0, 0, 0}, acc1[4] = {0, 0, 0, 0};
  for (int k0 = 0; k0 < 128; k0 += 64) {
#pragma unroll
    for (int it = 0; it < 8; ++it) {
      int idx4 = tid + it * 256;
      int kk = idx4 >> 5, jq = idx4 & 31;
      int j = jq * 4;
      float4 wv;
      if (j < 64) wv = *(const float4*)&W2[(k0 + kk) * 64 + j];
      else        wv = *(const float4*)&W3[(k0 + kk) * 64 + (j - 64)];
      *(float4*)&ws[kk][j] = wv;
    }
    __syncthreads();
#pragma unroll 8
    for (int kk = 0; kk < 64; ++kk) {
      float a0 = xsf[r0][k0 + kk], a1 = xsf[r0 + 1][k0 + kk];
      float4 wv = *(const float4*)&ws[kk][j0];
      acc0[0] += a0 * wv.x; acc0[1] += a0 * wv.y; acc0[2] += a0 * wv.z; acc0[3] += a0 * wv.w;
      acc1[0] += a1 * wv.x; acc1[1] += a1 * wv.y; acc1[2] += a1 * wv.z; acc1[3] += a1 * wv.w;
    }
    __syncthreads();
  }
  {
    float4 bb = (j0 < 64) ? *(const float4*)&b2[j0] : *(const float4*)&b3[j0 - 64];
    zs[r0][j0 + 0] = acc0[0] + bb.x; zs[r0][j0 + 1] = acc0[1] + bb.y;
    zs[r0][j0 + 2] = acc0[2] + bb.z; zs[r0][j0 + 3] = acc0[3] + bb.w;
    zs[r0 + 1][j0 + 0] = acc1[0] + bb.x; zs[r0 + 1][j0 + 1] = acc1[1] + bb.y;
    zs[r0 + 1][j0 + 2] = acc1[2] + bb.z; zs[r0 + 1][j0 + 3] = acc1[3] + bb.w;
  }
  __syncthreads();

  // phase C: reparam + bf16 split
  {
    const int r = tid >> 4;
    const int jj = (tid & 15) * 4;
    float4 mn = *(const float4*)&zs[r][jj];
    float4 ls = *(const float4*)&zs[r][64 + jj];
    float4 nz = *(const float4*)&noise[(row0 + r) * 64 + jj];
    float z0 = mn.x + nz.x * __expf(ls.x);
    float z1 = mn.y + nz.y * __expf(ls.y);
    float z2 = mn.z + nz.z * __expf(ls.z);
    float z3 = mn.w + nz.w * __expf(ls.w);
    ushort4e hh, ll;
    hh[0] = f32_to_bf16(z0); ll[0] = f32_to_bf16(z0 - bf16_to_f32(hh[0]));
    hh[1] = f32_to_bf16(z1); ll[1] = f32_to_bf16(z1 - bf16_to_f32(hh[1]));
    hh[2] = f32_to_bf16(z2); ll[2] = f32_to_bf16(z2 - bf16_to_f32(hh[2]));
    hh[3] = f32_to_bf16(z3); ll[3] = f32_to_bf16(z3 - bf16_to_f32(hh[3]));
    *(ushort4e*)&zh[(row0 + r) * 64 + jj] = hh;
    *(ushort4e*)&zl[(row0 + r) * 64 + jj] = ll;
  }
}

// out = sigmoid(z@z^T), 128x128 tile / 4 waves, each wave 64x64.
// zh/zl row+col tiles staged in LDS (64 KB, XOR-swizzled chunk^=row&7).
// Operand-swapped MFMA -> lane holds 4 consecutive cols of one row ->
// f32x4 stores; regular (cached) stores so L2 merges 64 B row-segments.
__global__ __launch_bounds__(256) void k_decode(const unsigned short* __restrict__ zh,
                                                const unsigned short* __restrict__ zl,
                                                float* __restrict__ out, int n) {
  __shared__ short zhr[128][64];
  __shared__ short zlr[128][64];
  __shared__ short zhc[128][64];
  __shared__ short zlc[128][64];
  const int tid = threadIdx.x;
  const int R0 = blockIdx.y * 128;
  const int C0 = blockIdx.x * 128;

  {
    const int seg = tid & 7;
#pragma unroll
    for (int p = 0; p < 4; ++p) {
      const int rr = (p << 5) + (tid >> 3);
      const int sw = (seg ^ (rr & 7)) * 8;
      short8 vhr = *(const short8*)&zh[(size_t)(R0 + rr) * 64 + seg * 8];
      short8 vlr = *(const short8*)&zl[(size_t)(R0 + rr) * 64 + seg * 8];
      short8 vhc = *(const short8*)&zh[(size_t)(C0 + rr) * 64 + seg * 8];
      short8 vlc = *(const short8*)&zl[(size_t)(C0 + rr) * 64 + seg * 8];
      *(short8*)&zhr[rr][sw] = vhr;
      *(short8*)&zlr[rr][sw] = vlr;
      *(short8*)&zhc[rr][sw] = vhc;
      *(short8*)&zlc[rr][sw] = vlc;
    }
  }
  __syncthreads();

  const int wave = tid >> 6, lane = tid & 63;
  const int lr0 = (wave >> 1) * 64;
  const int lc0 = (wave & 1) * 64;
  const int lrow = lane & 15;
  const int quad = lane >> 4;
  f32x4 acc[4][4];
#pragma unroll
  for (int m = 0; m < 4; ++m)
#pragma unroll
    for (int nn = 0; nn < 4; ++nn) acc[m][nn] = (f32x4){0.0f, 0.0f, 0.0f, 0.0f};

#pragma unroll
  for (int kc = 0; kc < 64; kc += 32) {
    const int cb = (kc >> 3) + quad;
    short8 rh[4], rl[4], ch[4], cl[4];
#pragma unroll
    for (int m = 0; m < 4; ++m) {
      int row = lr0 + m * 16 + lrow;
      int sw = (cb ^ (row & 7)) * 8;
      rh[m] = *(const short8*)&zhr[row][sw];
      rl[m] = *(const short8*)&zlr[row][sw];
    }
#pragma unroll
    for (int nn = 0; nn < 4; ++nn) {
      int row = lc0 + nn * 16 + lrow;
      int sw = (cb ^ (row & 7)) * 8;
      ch[nn] = *(const short8*)&zhc[row][sw];
      cl[nn] = *(const short8*)&zlc[row][sw];
    }
#pragma unroll
    for (int m = 0; m < 4; ++m)
#pragma unroll
      for (int nn = 0; nn < 4; ++nn) {
        acc[m][nn] = __builtin_amdgcn_mfma_f32_16x16x32_bf16(ch[nn], rh[m], acc[m][nn], 0, 0, 0);
        acc[m][nn] = __builtin_amdgcn_mfma_f32_16x16x32_bf16(cl[nn], rh[m], acc[m][nn], 0, 0, 0);
        acc[m][nn] = __builtin_amdgcn_mfma_f32_16x16x32_bf16(ch[nn], rl[m], acc[m][nn], 0, 0, 0);
      }
  }

  // transposed C layout: lane holds row (R0+lr0+m*16+lrow), cols quad*4+r
#pragma unroll
  for (int m = 0; m < 4; ++m) {
    int gr = R0 + lr0 + m * 16 + lrow;
    if (gr >= n) continue;
#pragma unroll
    for (int nn = 0; nn < 4; ++nn) {
      int c0 = C0 + lc0 + nn * 16 + quad * 4;
      if (c0 >= n) continue;
      f32x4 v;
      v[0] = sigmoidf(acc[m][nn][0]);
      v[1] = sigmoidf(acc[m][nn][1]);
      v[2] = sigmoidf(acc[m][nn][2]);
      v[3] = sigmoidf(acc[m][nn][3]);
      *(f32x4*)&out[(size_t)gr * n + c0] = v;
    }
  }
}

extern "C" void kernel_launch(void* const* d_in, const int* in_sizes, int n_in,
                              void* d_out, int out_size, void* d_ws, size_t ws_size,
                              hipStream_t stream) {
  const float* x     = (const float*)d_in[0];
  const int*   ei    = (const int*)d_in[1];
  const float* ew    = (const float*)d_in[2];
  const float* noise = (const float*)d_in[3];
  const float* W1    = (const float*)d_in[4];
  const float* b1    = (const float*)d_in[5];
  const float* W2    = (const float*)d_in[6];
  const float* b2    = (const float*)d_in[7];
  const float* W3    = (const float*)d_in[8];
  const float* b3    = (const float*)d_in[9];
  const int E = in_sizes[2];
  const int n = Nn;
  const int* row = ei;
  const int* col = ei + E;

  // d_ws: deg/dis (10240 f) + cnt (10240 i) + zh + zl (~2.6 MB)
  float* dis = (float*)d_ws;
  int*   cnt = (int*)((char*)d_ws + 10240 * 4);
  unsigned short* zh = (unsigned short*)((char*)d_ws + 81920);
  unsigned short* zl = zh + NpK;

  // big scratch in d_out (all dead before k_decode rewrites d_out)
  float* S = (float*)d_out;
  float* hw1   = S;                        // 10240*128
  float* h     = S + 1310720;              // 10240*128
  float* csr_w = S + 5242880;              // E
  int* csr_src = (int*)(S + 5402880);      // E
  int* ofs     = (int*)(S + 5562880);      // n+1
  int* ofs2    = (int*)(S + 5572896);      // n+1

  hipMemsetAsync(d_ws, 0, 81920, stream);  // deg = 0, cnt = 0

  k_front<<<782, 256, 0, stream>>>(x, W1, hw1, col, ew, dis, cnt, E);
  k_mid<<<48, 256, 0, stream>>>(cnt, ofs, ofs2, dis, zh, zl);
  k_fill<<<(E + 255) / 256, 256, 0, stream>>>(row, col, ew, dis, ofs2, csr_src, csr_w, E);

  k_agg<<<(n + 3) / 4, 256, 0, stream>>>(ofs, csr_src, csr_w, hw1, dis, b1, h, n);
  k_aggemm<<<n / 16, 256, 0, stream>>>(ofs, csr_src, csr_w, h, dis, W2, W3, b2, b3,
                                       noise, zh, zl);

  dim3 g((n + 127) / 128, (n + 127) / 128);
  k_decode<<<g, 256, 0, stream>>>(zh, zl, (float*)d_out, n);
}